// Round 3
// baseline (222.212 us; speedup 1.0000x reference)
//
#include <hip/hip_runtime.h>
#include <hip/hip_cooperative_groups.h>

namespace cg = cooperative_groups;

#define Bb 16
#define Ll 2048
#define Ee 256
#define E4 64
#define BPB 32          // blocks per batch
#define RPB 64          // rows per block
#define NBLK (Bb * BPB) // 512 total blocks

// workspace layout (floats). No zero-init required: partial slots are only
// read when active (r0 < len), accumulator reductions iterate nblk slots.
#define P1_OFF 0                          // [16][32][256] phase-A partial row sums
#define T_OFF  (P1_OFF + Bb*BPB*Ee)       // [16][256] t = s @ Wk
#define C_OFF  (T_OFF + Bb*Ee)            // [16]      c = s . bk
#define P2_OFF (C_OFF + 16)               // [16][32][256] phase-C partial u
#define WP_OFF (P2_OFF + Bb*BPB*Ee)       // [16][32]  phase-C partial W

__global__ void __launch_bounds__(256, 2) fused_all(
    const float* __restrict__ x, const int* __restrict__ lengths,
    const float* __restrict__ Wq, const float* __restrict__ bq,
    const float* __restrict__ Wk, const float* __restrict__ bk,
    const float* __restrict__ Wv, const float* __restrict__ bv,
    float* __restrict__ out, float* __restrict__ ws)
{
    cg::grid_group grid = cg::this_grid();
    const int tid  = threadIdx.x;
    const int lane = tid & 63;
    const int wid  = tid >> 6;
    const int blk  = blockIdx.x;
    const int b    = blk >> 5;   // batch for phases A/C
    const int i    = blk & 31;   // sub-block within batch
    const int len  = lengths[b];

    float* P1 = ws + P1_OFF;
    float* T  = ws + T_OFF;
    float* C  = ws + C_OFF;
    float* P2 = ws + P2_OFF;
    float* WP = ws + WP_OFF;

    __shared__ float4 part[256];             // 4 KB cross-wave reduce
    __shared__ alignas(16) float sh_a[Ee];   // xs / u
    __shared__ alignas(16) float sh_b[Ee];   // s
    __shared__ float cred[4];
    __shared__ float wsum_sh;

    const float4* xb = (const float4*)(x + (size_t)b * Ll * Ee);

    // ---- Phase A: partial sums of valid rows -> P1[b][i][:] ----
    {
        const int r0 = i * RPB;
        if (r0 < len) {
            const int r1 = min(r0 + RPB, len);
            float4 acc = {0.f, 0.f, 0.f, 0.f};
            for (int r = r0 + wid; r < r1; r += 4) {
                float4 v = xb[(size_t)r * E4 + lane];
                acc.x += v.x; acc.y += v.y; acc.z += v.z; acc.w += v.w;
            }
            part[tid] = acc;
            __syncthreads();
            if (tid < 64) {
                float4 a = part[tid], b1 = part[64+tid], c1 = part[128+tid], d1 = part[192+tid];
                float4 s4 = {a.x+b1.x+c1.x+d1.x, a.y+b1.y+c1.y+d1.y,
                             a.z+b1.z+c1.z+d1.z, a.w+b1.w+c1.w+d1.w};
                ((float4*)(P1 + ((size_t)(b * BPB + i)) * Ee))[tid] = s4;
            }
        }
    }
    grid.sync();

    // ---- Phase B: 16 blocks compute s = Xsum@Wq^T + len*bq; t = s@Wk; c = s.bk ----
    if (blk < Bb) {
        const int bb = blk;
        const int blen = lengths[bb];
        const int nblk = (blen + RPB - 1) / RPB;
        float a = 0.f;
        for (int j = 0; j < nblk; ++j) a += P1[((size_t)(bb * BPB + j)) * Ee + tid];
        sh_a[tid] = a;
        __syncthreads();
        {
            const float4* wrow = (const float4*)(Wq + (size_t)tid * Ee);
            const float4* xv4  = (const float4*)sh_a;
            float acc = 0.f;
#pragma unroll 8
            for (int j = 0; j < E4; ++j) {
                float4 w = wrow[j]; float4 v = xv4[j];
                acc += w.x*v.x + w.y*v.y + w.z*v.z + w.w*v.w;
            }
            sh_b[tid] = acc + (float)blen * bq[tid];
        }
        __syncthreads();
        float acc = 0.f;
#pragma unroll 8
        for (int f = 0; f < Ee; ++f) acc += sh_b[f] * Wk[(size_t)f * Ee + tid];
        T[bb * Ee + tid] = acc;
        float p = sh_b[tid] * bk[tid];
#pragma unroll
        for (int m = 32; m; m >>= 1) p += __shfl_xor(p, m, 64);
        if (lane == 0) cred[wid] = p;
        __syncthreads();
        if (tid == 0) C[bb] = cred[0] + cred[1] + cred[2] + cred[3];
    }
    grid.sync();

    // ---- Phase C: per valid row w = x.t + c; partial u,W -> P2/WP ----
    {
        const int r0 = i * RPB;
        if (r0 < len) {
            const int r1 = min(r0 + RPB, len);
            const float4 tv = ((const float4*)(T + b * Ee))[lane];
            const float  cb = C[b];
            float4 uacc = {0.f, 0.f, 0.f, 0.f};
            float  wacc = 0.f;
            for (int r = r0 + wid; r < r1; r += 4) {
                float4 xv = xb[(size_t)r * E4 + lane];
                float d = xv.x*tv.x + xv.y*tv.y + xv.z*tv.z + xv.w*tv.w;
#pragma unroll
                for (int m = 32; m; m >>= 1) d += __shfl_xor(d, m, 64);
                float w = d + cb;
                uacc.x += w*xv.x; uacc.y += w*xv.y; uacc.z += w*xv.z; uacc.w += w*xv.w;
                wacc += w;   // w is wave-uniform after the full-wave reduce
            }
            part[tid] = uacc;
            if (lane == 0) cred[wid] = wacc;
            __syncthreads();
            if (tid < 64) {
                float4 a = part[tid], b1 = part[64+tid], c1 = part[128+tid], d1 = part[192+tid];
                float4 s4 = {a.x+b1.x+c1.x+d1.x, a.y+b1.y+c1.y+d1.y,
                             a.z+b1.z+c1.z+d1.z, a.w+b1.w+c1.w+d1.w};
                ((float4*)(P2 + ((size_t)(b * BPB + i)) * Ee))[tid] = s4;
            }
            if (tid == 0) WP[b * BPB + i] = cred[0] + cred[1] + cred[2] + cred[3];
        }
    }
    grid.sync();

    // ---- Phase D: 16 blocks reduce u,W and emit out = (Wv.u + bv*W)/L ----
    if (blk < Bb) {
        const int bb = blk;
        const int blen = lengths[bb];
        const int nblk = (blen + RPB - 1) / RPB;
        float a = 0.f;
        for (int j = 0; j < nblk; ++j) a += P2[((size_t)(bb * BPB + j)) * Ee + tid];
        sh_a[tid] = a;
        if (wid == 0) {   // first wave reduces the 32 W partials
            float p = (lane < nblk) ? WP[bb * BPB + lane] : 0.f;
#pragma unroll
            for (int m = 32; m; m >>= 1) p += __shfl_xor(p, m, 64);
            if (lane == 0) wsum_sh = p;
        }
        __syncthreads();
        const float4* wrow = (const float4*)(Wv + (size_t)tid * Ee);
        const float4* u4   = (const float4*)sh_a;
        float acc = 0.f;
#pragma unroll 8
        for (int j = 0; j < E4; ++j) {
            float4 w = wrow[j]; float4 v = u4[j];
            acc += w.x*v.x + w.y*v.y + w.z*v.z + w.w*v.w;
        }
        out[bb * Ee + tid] = (acc + bv[tid] * wsum_sh) * (1.0f / (float)Ll);
    }
}

extern "C" void kernel_launch(void* const* d_in, const int* in_sizes, int n_in,
                              void* d_out, int out_size, void* d_ws, size_t ws_size,
                              hipStream_t stream) {
    const float* x       = (const float*)d_in[0];
    const int*   lengths = (const int*)d_in[1];
    const float* Wq      = (const float*)d_in[2];
    const float* bq      = (const float*)d_in[3];
    const float* Wk      = (const float*)d_in[4];
    const float* bk      = (const float*)d_in[5];
    const float* Wv      = (const float*)d_in[6];
    const float* bv      = (const float*)d_in[7];
    float* out = (float*)d_out;
    float* ws  = (float*)d_ws;

    void* args[] = {(void*)&x, (void*)&lengths, (void*)&Wq, (void*)&bq,
                    (void*)&Wk, (void*)&bk, (void*)&Wv, (void*)&bv,
                    (void*)&out, (void*)&ws};
    hipLaunchCooperativeKernel(reinterpret_cast<const void*>(&fused_all),
                               dim3(NBLK), dim3(256), args, 0, stream);
}

// Round 4
// 90.689 us; speedup vs baseline: 2.4503x; 2.4503x over previous
//
#include <hip/hip_runtime.h>

#define Bb 16
#define Ll 2048
#define Ee 256
#define E4 64
#define BPB 32          // blocks per batch
#define RPB 64          // rows per block

// ws layout: first 32 ints are ticket counters (zeroed by init each call),
// then float regions. Partial slots need no zero-init: only active slots
// (j < nblk) are ever read.
#define CNT_A 0
#define CNT_B 16
#define P1_OFF 32                          // [16][32][256] phase-A partials
#define T_OFF  (P1_OFF + Bb*BPB*Ee)        // [16][256] t
#define C_OFF  (T_OFF + Bb*Ee)             // [16]      c
#define P2_OFF (C_OFF + 16)                // [16][32][256] phase-C u partials
#define WP_OFF (P2_OFF + Bb*BPB*Ee)        // [16][32]  phase-C W partials

__global__ void __launch_bounds__(64) k_init(float* ws) {
    if (threadIdx.x < 32) ((int*)ws)[threadIdx.x] = 0;
}

// Phase A partials; last block per batch computes s,t,c.
__global__ void __launch_bounds__(256) kA(
    const float* __restrict__ x, const int* __restrict__ lengths,
    const float* __restrict__ Wq, const float* __restrict__ bq,
    const float* __restrict__ Wk, const float* __restrict__ bk,
    float* __restrict__ ws)
{
    const int tid  = threadIdx.x;
    const int lane = tid & 63;
    const int wid  = tid >> 6;
    const int blk  = blockIdx.x;
    const int b    = blk >> 5;
    const int i    = blk & 31;
    const int len  = lengths[b];

    float* P1 = ws + P1_OFF;
    float* T  = ws + T_OFF;
    float* C  = ws + C_OFF;
    int* cntA = (int*)ws + CNT_A;

    __shared__ float4 part[256];
    __shared__ alignas(16) float sh_a[Ee];
    __shared__ alignas(16) float sh_s[Ee];
    __shared__ float cred[4];
    __shared__ int isLast;

    const float4* xb = (const float4*)(x + (size_t)b * Ll * Ee);
    const int r0 = i * RPB;
    if (r0 < len) {
        const int r1 = min(r0 + RPB, len);
        float4 acc = {0.f, 0.f, 0.f, 0.f};
        for (int r = r0 + wid; r < r1; r += 4) {
            float4 v = xb[(size_t)r * E4 + lane];
            acc.x += v.x; acc.y += v.y; acc.z += v.z; acc.w += v.w;
        }
        part[tid] = acc;
        __syncthreads();
        if (tid < 64) {
            float4 a = part[tid], b1 = part[64+tid], c1 = part[128+tid], d1 = part[192+tid];
            float4 s4 = {a.x+b1.x+c1.x+d1.x, a.y+b1.y+c1.y+d1.y,
                         a.z+b1.z+c1.z+d1.z, a.w+b1.w+c1.w+d1.w};
            ((float4*)(P1 + ((size_t)(b * BPB + i)) * Ee))[tid] = s4;
        }
    }
    __syncthreads();                       // all stores drained (vmcnt0 before barrier)
    if (tid == 0) {
        __threadfence();                   // release P1 partials device-wide
        int old = atomicAdd(&cntA[b], 1);
        isLast = (old == BPB - 1);
    }
    __syncthreads();
    if (!isLast) return;
    __threadfence();                       // acquire other blocks' partials

    const int nblk = (len + RPB - 1) / RPB;
    float a = 0.f;
    for (int j = 0; j < nblk; ++j) a += P1[((size_t)(b * BPB + j)) * Ee + tid];
    sh_a[tid] = a;
    __syncthreads();
    {
        const float4* wrow = (const float4*)(Wq + (size_t)tid * Ee);
        const float4* xv4  = (const float4*)sh_a;
        float acc = 0.f;
#pragma unroll 8
        for (int j = 0; j < E4; ++j) {
            float4 w = wrow[j]; float4 v = xv4[j];
            acc += w.x*v.x + w.y*v.y + w.z*v.z + w.w*v.w;
        }
        sh_s[tid] = acc + (float)len * bq[tid];
    }
    __syncthreads();
    float acc = 0.f;
#pragma unroll 8
    for (int f = 0; f < Ee; ++f) acc += sh_s[f] * Wk[(size_t)f * Ee + tid];
    T[b * Ee + tid] = acc;
    float p = sh_s[tid] * bk[tid];
#pragma unroll
    for (int m = 32; m; m >>= 1) p += __shfl_xor(p, m, 64);
    if (lane == 0) cred[wid] = p;
    __syncthreads();
    if (tid == 0) C[b] = cred[0] + cred[1] + cred[2] + cred[3];
}

// Phase C partials; last block per batch reduces u,W and writes out.
__global__ void __launch_bounds__(256) kB(
    const float* __restrict__ x, const int* __restrict__ lengths,
    const float* __restrict__ Wv, const float* __restrict__ bv,
    float* __restrict__ ws, float* __restrict__ out)
{
    const int tid  = threadIdx.x;
    const int lane = tid & 63;
    const int wid  = tid >> 6;
    const int blk  = blockIdx.x;
    const int b    = blk >> 5;
    const int i    = blk & 31;
    const int len  = lengths[b];

    const float* T  = ws + T_OFF;
    const float* C  = ws + C_OFF;
    float* P2 = ws + P2_OFF;
    float* WP = ws + WP_OFF;
    int* cntB = (int*)ws + CNT_B;

    __shared__ float4 part[256];
    __shared__ alignas(16) float sh_a[Ee];
    __shared__ float cred[4];
    __shared__ float wsum_sh;
    __shared__ int isLast;

    const float4* xb = (const float4*)(x + (size_t)b * Ll * Ee);
    const int r0 = i * RPB;
    if (r0 < len) {
        const int r1 = min(r0 + RPB, len);
        const float4 tv = ((const float4*)(T + b * Ee))[lane];
        const float  cb = C[b];
        float4 uacc = {0.f, 0.f, 0.f, 0.f};
        float  wacc = 0.f;
        for (int r = r0 + wid; r < r1; r += 4) {
            float4 xv = xb[(size_t)r * E4 + lane];
            float d = xv.x*tv.x + xv.y*tv.y + xv.z*tv.z + xv.w*tv.w;
#pragma unroll
            for (int m = 32; m; m >>= 1) d += __shfl_xor(d, m, 64);
            float w = d + cb;
            uacc.x += w*xv.x; uacc.y += w*xv.y; uacc.z += w*xv.z; uacc.w += w*xv.w;
            wacc += w;                     // wave-uniform
        }
        part[tid] = uacc;
        if (lane == 0) cred[wid] = wacc;
        __syncthreads();
        if (tid < 64) {
            float4 a = part[tid], b1 = part[64+tid], c1 = part[128+tid], d1 = part[192+tid];
            float4 s4 = {a.x+b1.x+c1.x+d1.x, a.y+b1.y+c1.y+d1.y,
                         a.z+b1.z+c1.z+d1.z, a.w+b1.w+c1.w+d1.w};
            ((float4*)(P2 + ((size_t)(b * BPB + i)) * Ee))[tid] = s4;
        }
        if (tid == 0) WP[b * BPB + i] = cred[0] + cred[1] + cred[2] + cred[3];
    }
    __syncthreads();
    if (tid == 0) {
        __threadfence();
        int old = atomicAdd(&cntB[b], 1);
        isLast = (old == BPB - 1);
    }
    __syncthreads();
    if (!isLast) return;
    __threadfence();

    const int nblk = (len + RPB - 1) / RPB;
    float a = 0.f;
    for (int j = 0; j < nblk; ++j) a += P2[((size_t)(b * BPB + j)) * Ee + tid];
    sh_a[tid] = a;
    if (wid == 0) {
        float p = (lane < nblk) ? WP[b * BPB + lane] : 0.f;
#pragma unroll
        for (int m = 32; m; m >>= 1) p += __shfl_xor(p, m, 64);
        if (lane == 0) wsum_sh = p;
    }
    __syncthreads();
    const float4* wrow = (const float4*)(Wv + (size_t)tid * Ee);
    const float4* u4   = (const float4*)sh_a;
    float acc = 0.f;
#pragma unroll 8
    for (int j = 0; j < E4; ++j) {
        float4 w = wrow[j]; float4 v = u4[j];
        acc += w.x*v.x + w.y*v.y + w.z*v.z + w.w*v.w;
    }
    out[b * Ee + tid] = (acc + bv[tid] * wsum_sh) * (1.0f / (float)Ll);
}

extern "C" void kernel_launch(void* const* d_in, const int* in_sizes, int n_in,
                              void* d_out, int out_size, void* d_ws, size_t ws_size,
                              hipStream_t stream) {
    const float* x       = (const float*)d_in[0];
    const int*   lengths = (const int*)d_in[1];
    const float* Wq      = (const float*)d_in[2];
    const float* bq      = (const float*)d_in[3];
    const float* Wk      = (const float*)d_in[4];
    const float* bk      = (const float*)d_in[5];
    const float* Wv      = (const float*)d_in[6];
    const float* bv      = (const float*)d_in[7];
    float* out = (float*)d_out;
    float* ws  = (float*)d_ws;

    k_init<<<1, 64, 0, stream>>>(ws);
    kA<<<Bb * BPB, 256, 0, stream>>>(x, lengths, Wq, bq, Wk, bk, ws);
    kB<<<Bb * BPB, 256, 0, stream>>>(x, lengths, Wv, bv, ws, out);
}

// Round 5
// 39.688 us; speedup vs baseline: 5.5989x; 2.2850x over previous
//
#include <hip/hip_runtime.h>

#define Bb 16
#define Ll 2048
#define Ee 256
#define E4 64
#define BPB 32          // k1/k3 blocks per batch (64 rows each)
#define RPB 64
#define JT 16           // k2 blocks per batch (t f-slices)
#define FS (Ee / JT)    // 16 f-rows per slice

// ws layout (floats). No zero-init needed: P1/TP slots are written before read
// (only active P1 slots are read), U/W are zeroed by k2 (ordered by dispatch).
#define P1_OFF 0                        // [16][32][256] row-sum partials
#define TP_OFF (P1_OFF + Bb*BPB*Ee)     // [16][16][256] t partials (over f-slices)
#define C_OFF  (TP_OFF + Bb*JT*Ee)      // [16] c = s.bk
#define U_OFF  (C_OFF + Bb)             // [16][256] u accumulator
#define W_OFF  (U_OFF + Bb*Ee)          // [16] W accumulator

// k1: partial sums of valid rows -> P1[b][i][:]
__global__ void __launch_bounds__(256) k1(const float* __restrict__ x,
                                          const int* __restrict__ lengths,
                                          float* __restrict__ P1) {
    const int b = blockIdx.y, i = blockIdx.x;
    const int len = lengths[b];
    const int r0 = i * RPB;
    if (r0 >= len) return;
    const int r1 = min(r0 + RPB, len);
    const int tid = threadIdx.x, lane = tid & 63, wid = tid >> 6;
    const float4* xb = (const float4*)(x + (size_t)b * Ll * Ee);
    float4 acc = {0.f, 0.f, 0.f, 0.f};
    for (int r = r0 + wid; r < r1; r += 4) {
        float4 v = xb[(size_t)r * E4 + lane];
        acc.x += v.x; acc.y += v.y; acc.z += v.z; acc.w += v.w;
    }
    __shared__ float4 part[256];
    part[tid] = acc;
    __syncthreads();
    if (tid < 64) {
        float4 a = part[tid], b1 = part[64+tid], c1 = part[128+tid], d1 = part[192+tid];
        float4 s4 = {a.x+b1.x+c1.x+d1.x, a.y+b1.y+c1.y+d1.y,
                     a.z+b1.z+c1.z+d1.z, a.w+b1.w+c1.w+d1.w};
        ((float4*)(P1 + ((size_t)(b * BPB + i)) * Ee))[tid] = s4;
    }
}

// k2: block (b,j): reduce P1 -> Xsum, compute full s (redundant per j),
// emit t-partial for f-slice j. j==0 also emits C and zeroes U/W.
__global__ void __launch_bounds__(256) k2(const float* __restrict__ P1,
                                          const int* __restrict__ lengths,
                                          const float* __restrict__ Wq,
                                          const float* __restrict__ bq,
                                          const float* __restrict__ Wk,
                                          const float* __restrict__ bk,
                                          float* __restrict__ TP, float* __restrict__ C,
                                          float* __restrict__ U, float* __restrict__ W) {
    const int b = blockIdx.y, j = blockIdx.x;
    const int tid = threadIdx.x;
    const int len = lengths[b];
    const int nblk = (len + RPB - 1) / RPB;
    __shared__ alignas(16) float xs[Ee];
    __shared__ alignas(16) float s_sh[Ee];
    {
        float a = 0.f;
        for (int q = 0; q < nblk; ++q) a += P1[((size_t)(b * BPB + q)) * Ee + tid];
        xs[tid] = a;
    }
    __syncthreads();
    {
        const float4* wrow = (const float4*)(Wq + (size_t)tid * Ee);
        const float4* x4   = (const float4*)xs;
        float acc = 0.f;
#pragma unroll 8
        for (int q = 0; q < E4; ++q) {
            float4 w = wrow[q]; float4 v = x4[q];
            acc += w.x*v.x + w.y*v.y + w.z*v.z + w.w*v.w;
        }
        s_sh[tid] = acc + (float)len * bq[tid];
    }
    __syncthreads();
    // t-partial: f in [j*FS, (j+1)*FS)
    float tp = 0.f;
#pragma unroll
    for (int f0 = 0; f0 < FS; ++f0) {
        const int f = j * FS + f0;
        tp += s_sh[f] * Wk[(size_t)f * Ee + tid];
    }
    TP[((size_t)(b * JT + j)) * Ee + tid] = tp;
    if (j == 0) {
        U[b * Ee + tid] = 0.f;
        float p = s_sh[tid] * bk[tid];
#pragma unroll
        for (int m = 32; m; m >>= 1) p += __shfl_xor(p, m, 64);
        __shared__ float cred[4];
        if ((tid & 63) == 0) cred[tid >> 6] = p;
        __syncthreads();
        if (tid == 0) { C[b] = cred[0] + cred[1] + cred[2] + cred[3]; W[b] = 0.f; }
    }
}

// k3: reduce t-partials in-block, then weighted pass over 64 rows; accumulate U/W.
__global__ void __launch_bounds__(256) k3(const float* __restrict__ x,
                                          const int* __restrict__ lengths,
                                          const float* __restrict__ TP,
                                          const float* __restrict__ C,
                                          float* __restrict__ U, float* __restrict__ W) {
    const int b = blockIdx.y, i = blockIdx.x;
    const int len = lengths[b];
    const int r0 = i * RPB;
    if (r0 >= len) return;
    const int r1 = min(r0 + RPB, len);
    const int tid = threadIdx.x, lane = tid & 63, wid = tid >> 6;
    const float4* tp4 = (const float4*)(TP + (size_t)b * JT * Ee);
    float4 tv = {0.f, 0.f, 0.f, 0.f};
#pragma unroll
    for (int jj = 0; jj < JT; ++jj) {
        float4 t = tp4[jj * E4 + lane];
        tv.x += t.x; tv.y += t.y; tv.z += t.z; tv.w += t.w;
    }
    const float cb = C[b];
    const float4* xb = (const float4*)(x + (size_t)b * Ll * Ee);
    float4 uacc = {0.f, 0.f, 0.f, 0.f};
    float wacc = 0.f;
    for (int r = r0 + wid; r < r1; r += 4) {
        float4 xv = xb[(size_t)r * E4 + lane];
        float d = xv.x*tv.x + xv.y*tv.y + xv.z*tv.z + xv.w*tv.w;
#pragma unroll
        for (int m = 32; m; m >>= 1) d += __shfl_xor(d, m, 64);
        float w = d + cb;
        uacc.x += w*xv.x; uacc.y += w*xv.y; uacc.z += w*xv.z; uacc.w += w*xv.w;
        wacc += w;                       // wave-uniform
    }
    __shared__ float4 part[256];
    __shared__ float cw[4];
    part[tid] = uacc;
    if (lane == 0) cw[wid] = wacc;
    __syncthreads();
    if (tid < 64) {
        float4 a = part[tid], b1 = part[64+tid], c1 = part[128+tid], d1 = part[192+tid];
        float* ub = U + b * Ee + tid * 4;
        atomicAdd(ub + 0, a.x + b1.x + c1.x + d1.x);
        atomicAdd(ub + 1, a.y + b1.y + c1.y + d1.y);
        atomicAdd(ub + 2, a.z + b1.z + c1.z + d1.z);
        atomicAdd(ub + 3, a.w + b1.w + c1.w + d1.w);
    }
    if (tid == 0) atomicAdd(W + b, cw[0] + cw[1] + cw[2] + cw[3]);
}

// k4: block (b,j): out[b, j*64 + lane] for 64 e-rows; 4 waves split f.
__global__ void __launch_bounds__(256) k4(const float* __restrict__ U,
                                          const float* __restrict__ W,
                                          const float* __restrict__ Wv,
                                          const float* __restrict__ bv,
                                          float* __restrict__ out) {
    const int b = blockIdx.y, j = blockIdx.x;   // j in 0..3
    const int tid = threadIdx.x, lane = tid & 63, wid = tid >> 6;
    __shared__ float4 u4[E4];
    __shared__ float red[4][64];
    if (tid < E4) u4[tid] = ((const float4*)(U + b * Ee))[tid];
    __syncthreads();
    const int e = j * 64 + lane;
    const float4* wv = (const float4*)(Wv + (size_t)e * Ee);
    float acc = 0.f;
#pragma unroll
    for (int q = 0; q < 16; ++q) {
        float4 w = wv[wid * 16 + q]; float4 v = u4[wid * 16 + q];
        acc += w.x*v.x + w.y*v.y + w.z*v.z + w.w*v.w;
    }
    red[wid][lane] = acc;
    __syncthreads();
    if (wid == 0) {
        float r = red[0][lane] + red[1][lane] + red[2][lane] + red[3][lane];
        out[b * Ee + e] = (r + bv[e] * W[b]) * (1.0f / (float)Ll);
    }
}

extern "C" void kernel_launch(void* const* d_in, const int* in_sizes, int n_in,
                              void* d_out, int out_size, void* d_ws, size_t ws_size,
                              hipStream_t stream) {
    const float* x       = (const float*)d_in[0];
    const int*   lengths = (const int*)d_in[1];
    const float* Wq      = (const float*)d_in[2];
    const float* bq      = (const float*)d_in[3];
    const float* Wk      = (const float*)d_in[4];
    const float* bk      = (const float*)d_in[5];
    const float* Wv      = (const float*)d_in[6];
    const float* bv      = (const float*)d_in[7];
    float* out = (float*)d_out;
    float* ws  = (float*)d_ws;

    k1<<<dim3(BPB, Bb), 256, 0, stream>>>(x, lengths, ws + P1_OFF);
    k2<<<dim3(JT, Bb), 256, 0, stream>>>(ws + P1_OFF, lengths, Wq, bq, Wk, bk,
                                         ws + TP_OFF, ws + C_OFF, ws + U_OFF, ws + W_OFF);
    k3<<<dim3(BPB, Bb), 256, 0, stream>>>(x, lengths, ws + TP_OFF, ws + C_OFF,
                                          ws + U_OFF, ws + W_OFF);
    k4<<<dim3(4, Bb), 256, 0, stream>>>(ws + U_OFF, ws + W_OFF, Wv, bv, out);
}